// Round 3
// baseline (414.638 us; speedup 1.0000x reference)
//
#include <hip/hip_runtime.h>
#include <stdint.h>

typedef __attribute__((ext_vector_type(8))) __bf16 bf16x8;
typedef __attribute__((ext_vector_type(4))) float f32x4;

__device__ __forceinline__ void async_ld16(const void* g, void* l) {
  __builtin_amdgcn_global_load_lds(
      (const __attribute__((address_space(1))) unsigned int*)g,
      (__attribute__((address_space(3))) unsigned int*)l, 16, 0, 0);
}

__device__ __forceinline__ unsigned short f2bf(float x) {
  union { float f; unsigned int u; } v; v.f = x;
  unsigned int r = v.u + 0x7FFFu + ((v.u >> 16) & 1u);
  return (unsigned short)(r >> 16);
}

__device__ __forceinline__ float exp2_fast(float x) {
  return __builtin_amdgcn_exp2f(x);
}

// pack two fp32 -> bf16 pair in one dword: round-half-up + v_perm_b32
__device__ __forceinline__ unsigned int pack_bf2(float a, float b) {
  unsigned int ua = __builtin_bit_cast(unsigned int, a) + 0x8000u;
  unsigned int ub = __builtin_bit_cast(unsigned int, b) + 0x8000u;
  return __builtin_amdgcn_perm(ub, ua, 0x07060302u);
}

// ---------------- fused fp32->bf16 convert: x + in_proj_w + out_proj_w ----------------
__global__ void cvt3(const float* __restrict__ x, unsigned short* __restrict__ xd,
                     const float* __restrict__ w1, unsigned short* __restrict__ w1d,
                     const float* __restrict__ w2, unsigned short* __restrict__ w2d) {
  int i = blockIdx.x * 256 + threadIdx.x;
  const float* s; unsigned short* d; int off;
  if (i < 2097152)      { s = x;  d = xd;  off = i; }
  else if (i < 2883584) { s = w1; d = w1d; off = i - 2097152; }
  else                  { s = w2; d = w2d; off = i - 2883584; }
  float4 v = ((const float4*)s)[off];
  ushort4 o;
  o.x = f2bf(v.x); o.y = f2bf(v.y); o.z = f2bf(v.z); o.w = f2bf(v.w);
  ((ushort4*)d)[off] = o;
}

// ---------------- GEMM: C[m][n] = sum_k A[m][k]*B[n][k] + bias[n] ----------------
// 256x256 tile, BK=64, 512 threads (8 waves, 2M x 4N). Per K-tile: 4 phases
// {ds_read frags; stage one 16KB half-region; setprio(1) MFMA setprio(0);
// s_barrier + compiler memclobber}. ONE barrier per phase (WAR-safe).
// Counted-wait discipline (T4, m218's lever): TWO vmcnt(8) waits per tile,
// at end of ph1 (covers kh1 of this tile, issued 1 tile earlier) and end of
// ph3 (covers kh0 of next tile, issued ph2/ph3 of previous tile). Each wait
// point has 12 loads outstanding; oldest 4 are exactly the region consumed
// next -> vmcnt(8) is exact, keeps 8 loads permanently in flight, and every
// load is waited 4-6 phases after issue (vs 2.5 with the old vmcnt(4)/tile).
// XCD-swizzled block mapping (nwg per z-slice % 8 == 0 -> bijective).
__global__ __launch_bounds__(512, 2)
void gemm_bt(const unsigned short* __restrict__ A0, const unsigned short* __restrict__ A1,
             const unsigned short* __restrict__ B0, const unsigned short* __restrict__ B1,
             const float* __restrict__ bias0, const float* __restrict__ bias1,
             void* __restrict__ out0, void* __restrict__ out1,
             int N, int K, int f32out, int qlim, float qs) {
  __shared__ unsigned short As[2][2][256 * 32];  // [buf][khalf][row*32+col] 64 KB
  __shared__ unsigned short Bs[2][2][256 * 32];  // 64 KB
  int br = blockIdx.z;
  const unsigned short* A = br ? A1 : A0;
  const unsigned short* B = br ? B1 : B0;
  const float* bias = br ? bias1 : bias0;
  void* outp = br ? out1 : out0;

  // XCD-aware swizzle of (x,y) within this z-slice
  int gx = gridDim.x, gy = gridDim.y;
  int nwg = gx * gy;
  int flat = blockIdx.y * gx + blockIdx.x;
  int cpx = nwg >> 3;  // nwg % 8 == 0 for all our grids (384, 128)
  int swb = (flat & 7) * cpx + (flat >> 3);
  int bxi = swb % gx, byi = swb / gx;

  int tid = threadIdx.x;
  int wave = tid >> 6, lane = tid & 63;
  int quad = lane >> 4, l16 = lane & 15;
  int wm = (wave >> 2) * 128;       // 2 M-groups of waves
  int wn = (wave & 3) * 64;         // 4 N-groups
  size_t bm = (size_t)byi * 256, bn = (size_t)bxi * 256;

  f32x4 acc[8][4];
  f32x4 zero = {0.f, 0.f, 0.f, 0.f};
#pragma unroll
  for (int i = 0; i < 8; i++)
#pragma unroll
    for (int j = 0; j < 4; j++) acc[i][j] = zero;

  // LDS read bases: frag (kh,mi): row = wm|wn + mi*16 + l16, swizzled chunk quad^((row>>1)&3)
  int swc = (quad ^ ((l16 >> 1) & 3)) * 16;
  const char* ArdB = (const char*)As + (wm + l16) * 64 + swc;
  const char* BrdB = (const char*)Bs + (wn + l16) * 64 + swc;

  // staging: thread t covers lds 16B-chunks t (rows 0..127) and 512+t (rows 128..255)
  // of each 16 KB (256x32) half-region; global source pre-swizzled to match reads.
  int row0 = tid >> 2, c0 = (tid & 3) ^ ((row0 >> 1) & 3);
  int row1 = row0 + 128, c1 = (tid & 3) ^ ((row1 >> 1) & 3);
  const char* Ag0 = (const char*)(A + (bm + row0) * (size_t)K) + c0 * 16;
  const char* Ag1 = (const char*)(A + (bm + row1) * (size_t)K) + c1 * 16;
  const char* Bg0 = (const char*)(B + (bn + row0) * (size_t)K) + c0 * 16;
  const char* Bg1 = (const char*)(B + (bn + row1) * (size_t)K) + c1 * 16;
  char* ldsA = (char*)As + tid * 16;
  char* ldsB = (char*)Bs + tid * 16;

#define STAGE_A(po_, kh_, koff_) do {                    \
    char* d_ = ldsA + (po_) + (kh_) * 16384;             \
    async_ld16(Ag0 + (koff_), d_);                       \
    async_ld16(Ag1 + (koff_), d_ + 8192); } while (0)
#define STAGE_B(po_, kh_, koff_) do {                    \
    char* d_ = ldsB + (po_) + (kh_) * 16384;             \
    async_ld16(Bg0 + (koff_), d_);                       \
    async_ld16(Bg1 + (koff_), d_ + 8192); } while (0)
#define LDA_F(po_, kh_, mi_) (*(const bf16x8*)(ArdB + (po_) + (kh_) * 16384 + (mi_) * 1024))
#define LDB_F(po_, kh_, ni_) (*(const bf16x8*)(BrdB + (po_) + (kh_) * 16384 + (ni_) * 1024))
// barrier + zero-cost compiler memory clobber: partitions memory-op ISSUE per
// phase (keeps vmcnt counting exact) without pinning the instruction scheduler.
#define BAR() do { __builtin_amdgcn_s_barrier(); asm volatile("" ::: "memory"); } while (0)
#define MFMAQ(mb_) do {                                                                              \
    acc[(mb_)+0][0] = __builtin_amdgcn_mfma_f32_16x16x32_bf16(b0, a0, acc[(mb_)+0][0], 0, 0, 0);     \
    acc[(mb_)+1][0] = __builtin_amdgcn_mfma_f32_16x16x32_bf16(b0, a1, acc[(mb_)+1][0], 0, 0, 0);     \
    acc[(mb_)+2][0] = __builtin_amdgcn_mfma_f32_16x16x32_bf16(b0, a2, acc[(mb_)+2][0], 0, 0, 0);     \
    acc[(mb_)+3][0] = __builtin_amdgcn_mfma_f32_16x16x32_bf16(b0, a3, acc[(mb_)+3][0], 0, 0, 0);     \
    acc[(mb_)+0][1] = __builtin_amdgcn_mfma_f32_16x16x32_bf16(b1, a0, acc[(mb_)+0][1], 0, 0, 0);     \
    acc[(mb_)+1][1] = __builtin_amdgcn_mfma_f32_16x16x32_bf16(b1, a1, acc[(mb_)+1][1], 0, 0, 0);     \
    acc[(mb_)+2][1] = __builtin_amdgcn_mfma_f32_16x16x32_bf16(b1, a2, acc[(mb_)+2][1], 0, 0, 0);     \
    acc[(mb_)+3][1] = __builtin_amdgcn_mfma_f32_16x16x32_bf16(b1, a3, acc[(mb_)+3][1], 0, 0, 0);     \
    acc[(mb_)+0][2] = __builtin_amdgcn_mfma_f32_16x16x32_bf16(b2, a0, acc[(mb_)+0][2], 0, 0, 0);     \
    acc[(mb_)+1][2] = __builtin_amdgcn_mfma_f32_16x16x32_bf16(b2, a1, acc[(mb_)+1][2], 0, 0, 0);     \
    acc[(mb_)+2][2] = __builtin_amdgcn_mfma_f32_16x16x32_bf16(b2, a2, acc[(mb_)+2][2], 0, 0, 0);     \
    acc[(mb_)+3][2] = __builtin_amdgcn_mfma_f32_16x16x32_bf16(b2, a3, acc[(mb_)+3][2], 0, 0, 0);     \
    acc[(mb_)+0][3] = __builtin_amdgcn_mfma_f32_16x16x32_bf16(b3, a0, acc[(mb_)+0][3], 0, 0, 0);     \
    acc[(mb_)+1][3] = __builtin_amdgcn_mfma_f32_16x16x32_bf16(b3, a1, acc[(mb_)+1][3], 0, 0, 0);     \
    acc[(mb_)+2][3] = __builtin_amdgcn_mfma_f32_16x16x32_bf16(b3, a2, acc[(mb_)+2][3], 0, 0, 0);     \
    acc[(mb_)+3][3] = __builtin_amdgcn_mfma_f32_16x16x32_bf16(b3, a3, acc[(mb_)+3][3], 0, 0, 0);     \
  } while (0)

  const int NT = K >> 6;  // 16 for K=1024

  // prologue: tile0 all 4 regions, tile1 kh0 regions (12 loads/thread)
  STAGE_A(0, 0, 0);       STAGE_B(0, 0, 0);
  STAGE_A(0, 1, 64);      STAGE_B(0, 1, 64);
  STAGE_A(32768, 0, 128); STAGE_B(32768, 0, 128);
  asm volatile("s_waitcnt vmcnt(4)" ::: "memory");  // tile0's 8 loads landed
  BAR();

  for (int j = 0; j < NT; ++j) {
    int po = (j & 1) * 32768;            // this tile's buffer
    int qo = po ^ 32768;                 // other buffer (tile j+1)
    int t1 = (j + 1 < NT) ? j + 1 : NT - 1;   // source clamp (dest is dead region)
    int t2 = (j + 2 < NT) ? j + 2 : NT - 1;
    int ko1 = t1 * 128 + 64;             // tile j+1, kh1 source byte offset
    int ko2 = t2 * 128;                  // tile j+2, kh0
    bf16x8 a0, a1, a2, a3, b0, b1, b2, b3;

    // ---- phase 0: kh0, mi 0-3 ----
    b0 = LDB_F(po, 0, 0); b1 = LDB_F(po, 0, 1); b2 = LDB_F(po, 0, 2); b3 = LDB_F(po, 0, 3);
    a0 = LDA_F(po, 0, 0); a1 = LDA_F(po, 0, 1); a2 = LDA_F(po, 0, 2); a3 = LDA_F(po, 0, 3);
    STAGE_A(qo, 1, ko1);
    __builtin_amdgcn_s_setprio(1); MFMAQ(0); __builtin_amdgcn_s_setprio(0);
    BAR();
    // ---- phase 1: kh0, mi 4-7 (B frags reused from regs) ----
    a0 = LDA_F(po, 0, 4); a1 = LDA_F(po, 0, 5); a2 = LDA_F(po, 0, 6); a3 = LDA_F(po, 0, 7);
    STAGE_B(qo, 1, ko1);
    __builtin_amdgcn_s_setprio(1); MFMAQ(4); __builtin_amdgcn_s_setprio(0);
    // W1: ensure THIS tile's kh1 (issued ph0/ph1 of previous tile) landed.
    // 12 loads outstanding here; oldest 4 = that region -> vmcnt(8) exact.
    asm volatile("s_waitcnt vmcnt(8)" ::: "memory");
    BAR();
    // ---- phase 2: kh1, mi 0-3 ----
    b0 = LDB_F(po, 1, 0); b1 = LDB_F(po, 1, 1); b2 = LDB_F(po, 1, 2); b3 = LDB_F(po, 1, 3);
    a0 = LDA_F(po, 1, 0); a1 = LDA_F(po, 1, 1); a2 = LDA_F(po, 1, 2); a3 = LDA_F(po, 1, 3);
    STAGE_A(po, 0, ko2);                 // kh0 of this buf is dead (read in ph0/1)
    __builtin_amdgcn_s_setprio(1); MFMAQ(0); __builtin_amdgcn_s_setprio(0);
    BAR();
    // ---- phase 3: kh1, mi 4-7 ----
    a0 = LDA_F(po, 1, 4); a1 = LDA_F(po, 1, 5); a2 = LDA_F(po, 1, 6); a3 = LDA_F(po, 1, 7);
    STAGE_B(po, 0, ko2);
    __builtin_amdgcn_s_setprio(1); MFMAQ(4); __builtin_amdgcn_s_setprio(0);
    // W0: ensure next tile's kh0 (issued ph2/ph3 of previous tile) landed.
    // 12 loads outstanding; oldest 4 = that region -> vmcnt(8) exact.
    asm volatile("s_waitcnt vmcnt(8)" ::: "memory");
    BAR();
  }

#undef STAGE_A
#undef STAGE_B
#undef LDA_F
#undef LDB_F
#undef BAR
#undef MFMAQ

#pragma unroll
  for (int mi = 0; mi < 8; mi++) {
    size_t rowg = bm + wm + mi * 16 + l16;
#pragma unroll
    for (int ni = 0; ni < 4; ni++) {
      size_t col = bn + wn + ni * 16 + quad * 4;
      float s = ((int)col < qlim) ? qs : 1.0f;
      float4 bv = *(const float4*)&bias[col];
      f32x4 a = acc[mi][ni];
      if (f32out) {
        float4 o = {(a[0] + bv.x) * s, (a[1] + bv.y) * s,
                    (a[2] + bv.z) * s, (a[3] + bv.w) * s};
        *(float4*)&((float*)outp)[rowg * N + col] = o;
      } else {
        ushort4 o;
        o.x = f2bf((a[0] + bv.x) * s); o.y = f2bf((a[1] + bv.y) * s);
        o.z = f2bf((a[2] + bv.z) * s); o.w = f2bf((a[3] + bv.w) * s);
        *(ushort4*)&((unsigned short*)outp)[rowg * N + col] = o;
      }
    }
  }
}

// ---------------- transpose V slice of qkv -> VT (key-permuted, dual-branch) ----------------
__device__ __forceinline__ int kperm(int p) {
  return (p & 0xC3) | ((p & 0x0C) << 2) | ((p & 0x30) >> 2);
}
__global__ void transpose_v(const unsigned short* __restrict__ q0, unsigned short* __restrict__ v0, int W0,
                            const unsigned short* __restrict__ q1, unsigned short* __restrict__ v1, int W1,
                            int zsplit) {
  __shared__ unsigned short tile[64][33];
  int z = blockIdx.z;
  const unsigned short* qkv; unsigned short* vt; int W, wb, yy;
  if (z < zsplit) { qkv = q0; vt = v0; W = W0; wb = z; yy = blockIdx.y; }
  else { qkv = q1; vt = v1; W = W1; int t = z - zsplit; wb = t >> 2; yy = blockIdx.y + 4 * (t & 3); }
  int c0 = blockIdx.x * 32, w0 = yy * 64;
  const unsigned short* src = qkv + (size_t)wb * W * 3072 + 2048;
  for (int i = threadIdx.y; i < 64; i += 8)
    tile[i][threadIdx.x] = src[(size_t)(w0 + i) * 3072 + c0 + threadIdx.x];
  __syncthreads();
  unsigned short* dst = vt + (size_t)wb * 1024 * W;
  for (int i = threadIdx.y; i < 32; i += 8) {
    int p0 = threadIdx.x, p1 = threadIdx.x + 32;
    dst[(size_t)(c0 + i) * W + w0 + p0] = tile[kperm(p0)][i];
    dst[(size_t)(c0 + i) * W + w0 + p1] = tile[kperm(p1)][i];
  }
}

// ---------------- fused flash attention, S^T, max-free softmax, dual-branch ----------------
__global__ __launch_bounds__(256)
void attn_fused(const unsigned short* __restrict__ qkv0, const unsigned short* __restrict__ vt0,
                unsigned short* __restrict__ ao0, int W0, int nb0,
                const unsigned short* __restrict__ qkv1, const unsigned short* __restrict__ vt1,
                unsigned short* __restrict__ ao1, int W1) {
  __shared__ unsigned short Ks[64 * 64];
  __shared__ unsigned short Vs[64 * 64];
  __shared__ unsigned int   Ps[4][16 * 32];
  int bid = blockIdx.x;
  const unsigned short *qkv, *vtb0; unsigned short* ao; int W, rel;
  if (bid < nb0) { qkv = qkv0; vtb0 = vt0; ao = ao0; W = W0; rel = bid; }
  else           { qkv = qkv1; vtb0 = vt1; ao = ao1; W = W1; rel = bid - nb0; }
  int gx = W >> 7;                       // 2 or 8
  int shift = (gx == 2) ? 1 : 3;
  int bx = rel & (gx - 1);
  int wbh = rel >> shift;
  int wb = wbh >> 4, h = wbh & 15;

  int tid = threadIdx.x;
  int wave = tid >> 6, lane = tid & 63;
  int quad = lane >> 4, l16 = lane & 15;
  int swz = l16 & 7;
  int q0w = bx * 128 + wave * 32;

  const unsigned short* qb = qkv + (size_t)wb * W * 3072 + h * 64;
  const unsigned short* kb = qb + 1024;
  const unsigned short* vtb = vtb0 + (size_t)wbh * 64 * W;

  bf16x8 qf[2][2];
  for (int cb = 0; cb < 2; cb++)
    for (int ch = 0; ch < 2; ch++)
      qf[cb][ch] = *(const bf16x8*)(qb + (size_t)(q0w + cb * 16 + l16) * 3072 +
                                    ch * 32 + quad * 8);

  f32x4 zero = {0.f, 0.f, 0.f, 0.f};
  f32x4 O[2][4];
  for (int cb = 0; cb < 2; cb++)
    for (int g = 0; g < 4; g++) O[cb][g] = zero;
  float l_i[2] = {0.f, 0.f};

  for (int k0 = 0; k0 < W; k0 += 64) {
    __syncthreads();
    for (int j = 0; j < 2; j++) {
      int c = j * 256 + tid;
      int row = c >> 3, sl = c & 7, ss = sl ^ (row & 7);
      async_ld16(kb + (size_t)(k0 + row) * 3072 + ss * 8, (char*)Ks + c * 16);
      async_ld16(vtb + (size_t)row * W + k0 + ss * 8,     (char*)Vs + c * 16);
    }
    __syncthreads();

    bf16x8 ak[4][2], vf[4][2];
#pragma unroll
    for (int i = 0; i < 4; i++)
#pragma unroll
      for (int ch = 0; ch < 2; ch++) {
        int sl = (ch * 4 + quad) ^ swz;
        ak[i][ch] = *(const bf16x8*)&Ks[(i * 16 + l16) * 64 + sl * 8];
        vf[i][ch] = *(const bf16x8*)&Vs[(i * 16 + l16) * 64 + sl * 8];
      }

    for (int cb = 0; cb < 2; cb++) {
      unsigned int pk[8];
      float sm = 0.f;
#pragma unroll
      for (int sub = 0; sub < 4; sub++) {
        f32x4 z = zero;
        z = __builtin_amdgcn_mfma_f32_16x16x32_bf16(ak[sub][0], qf[cb][0], z, 0, 0, 0);
        z = __builtin_amdgcn_mfma_f32_16x16x32_bf16(ak[sub][1], qf[cb][1], z, 0, 0, 0);
        float p0 = exp2_fast(z[0]), p1 = exp2_fast(z[1]);
        float p2 = exp2_fast(z[2]), p3 = exp2_fast(z[3]);
        sm += (p0 + p1) + (p2 + p3);
        pk[((sub & 1) * 2) + (sub >> 1) * 4]     = pack_bf2(p0, p1);
        pk[((sub & 1) * 2) + (sub >> 1) * 4 + 1] = pack_bf2(p2, p3);
      }
      sm += __shfl_xor(sm, 16);
      sm += __shfl_xor(sm, 32);
      l_i[cb] += sm;

      unsigned int* pw = &Ps[wave][0];
      uint4 u0 = {pk[0], pk[1], pk[2], pk[3]};
      uint4 u1 = {pk[4], pk[5], pk[6], pk[7]};
      *(uint4*)&pw[l16 * 32 + ((2 * quad) ^ swz) * 4]     = u0;
      *(uint4*)&pw[l16 * 32 + ((2 * quad + 1) ^ swz) * 4] = u1;

      bf16x8 pf[2];
#pragma unroll
      for (int ch = 0; ch < 2; ch++) {
        uint4 u = *(const uint4*)&pw[l16 * 32 + ((ch * 4 + quad) ^ swz) * 4];
        pf[ch] = __builtin_bit_cast(bf16x8, u);
      }
#pragma unroll
      for (int g = 0; g < 4; g++) {
        O[cb][g] = __builtin_amdgcn_mfma_f32_16x16x32_bf16(pf[0], vf[g][0], O[cb][g], 0, 0, 0);
        O[cb][g] = __builtin_amdgcn_mfma_f32_16x16x32_bf16(pf[1], vf[g][1], O[cb][g], 0, 0, 0);
      }
    }
  }

  for (int cb = 0; cb < 2; cb++) {
    float inv = 1.0f / l_i[cb];
    float ivr[4];
    for (int r = 0; r < 4; r++) ivr[r] = __shfl(inv, quad * 4 + r);
    for (int r = 0; r < 4; r++) {
      size_t rowg = (size_t)wb * W + q0w + cb * 16 + quad * 4 + r;
      for (int g = 0; g < 4; g++)
        ao[rowg * 1024 + h * 64 + g * 16 + l16] = f2bf(O[cb][g][r] * ivr[r]);
    }
  }
}

// ---------------- host ----------------
extern "C" void kernel_launch(void* const* d_in, const int* in_sizes, int n_in,
                              void* d_out, int out_size, void* d_ws, size_t ws_size,
                              hipStream_t stream) {
  const int D = 1024, TD = 3072, M = 8192;
  const float QS = 0.125f * 1.44269504089f;  // softmax scale * log2(e)
  const size_t PER = 46137344;               // bf16 elems per branch
  bool comb = ws_size >= (size_t)2 * PER * 2;

  unsigned short* Xb[2]; unsigned short* Wb[2]; unsigned short* Ob[2];
  unsigned short* qkv[2]; unsigned short* vt[2];
  for (int b = 0; b < 2; b++) {
    unsigned short* base = (unsigned short*)d_ws + (comb ? b * PER : 0);
    Xb[b]  = base;
    Wb[b]  = Xb[b] + 8388608;
    Ob[b]  = Wb[b] + 3145728;
    qkv[b] = Ob[b] + 1048576;
    vt[b]  = qkv[b] + 25165824;
  }
  float* outp = (float*)d_out;
  const float* x[2]   = {(const float*)d_in[0], (const float*)d_in[1]};
  const float* ipw[2] = {(const float*)d_in[2], (const float*)d_in[6]};
  const float* ipb[2] = {(const float*)d_in[3], (const float*)d_in[7]};
  const float* opw[2] = {(const float*)d_in[4], (const float*)d_in[8]};
  const float* opb[2] = {(const float*)d_in[5], (const float*)d_in[9]};
  const int Wd[2] = {256, 1024};

  if (comb) {
    for (int b = 0; b < 2; b++)
      cvt3<<<12288, 256, 0, stream>>>(x[b], Xb[b], ipw[b], Wb[b], opw[b], Ob[b]);
    gemm_bt<<<dim3(TD / 256, M / 256, 2), 512, 0, stream>>>(
        Xb[0], Xb[1], Wb[0], Wb[1], ipb[0], ipb[1], qkv[0], qkv[1],
        TD, D, 0, D, QS);
    transpose_v<<<dim3(32, 4, 64), dim3(32, 8), 0, stream>>>(
        qkv[0], vt[0], 256, qkv[1], vt[1], 1024, 32);
    attn_fused<<<2048, 256, 0, stream>>>(
        qkv[0], vt[0], Xb[0], 256, 1024, qkv[1], vt[1], Xb[1], 1024);
    gemm_bt<<<dim3(D / 256, M / 256, 2), 512, 0, stream>>>(
        Xb[0], Xb[1], Ob[0], Ob[1], opb[0], opb[1], outp, outp + 8388608,
        D, D, 1, 0, 1.0f);
  } else {
    for (int b = 0; b < 2; b++) {
      int W = Wd[b], nwb = M / W;
      cvt3<<<12288, 256, 0, stream>>>(x[b], Xb[b], ipw[b], Wb[b], opw[b], Ob[b]);
      gemm_bt<<<dim3(TD / 256, M / 256, 1), 512, 0, stream>>>(
          Xb[b], Xb[b], Wb[b], Wb[b], ipb[b], ipb[b], qkv[b], qkv[b],
          TD, D, 0, D, QS);
      if (b == 0)
        transpose_v<<<dim3(32, 4, 32), dim3(32, 8), 0, stream>>>(
            qkv[b], vt[b], W, qkv[b], vt[b], W, 32);
      else
        transpose_v<<<dim3(32, 4, 32), dim3(32, 8), 0, stream>>>(
            qkv[b], vt[b], W, qkv[b], vt[b], W, 0);
      int nb = (W >> 7) * nwb * 16;
      attn_fused<<<nb, 256, 0, stream>>>(
          qkv[b], vt[b], Xb[b], W, nb, qkv[b], vt[b], Xb[b], W);
      gemm_bt<<<dim3(D / 256, M / 256, 1), 512, 0, stream>>>(
          Xb[b], Xb[b], Ob[b], Ob[b], opb[b], opb[b],
          outp + (size_t)b * 8388608, outp + (size_t)b * 8388608,
          D, D, 1, 0, 1.0f);
    }
  }
}

// Round 4
// 413.476 us; speedup vs baseline: 1.0028x; 1.0028x over previous
//
#include <hip/hip_runtime.h>
#include <stdint.h>

typedef __attribute__((ext_vector_type(8))) __bf16 bf16x8;
typedef __attribute__((ext_vector_type(4))) float f32x4;

__device__ __forceinline__ void async_ld16(const void* g, void* l) {
  __builtin_amdgcn_global_load_lds(
      (const __attribute__((address_space(1))) unsigned int*)g,
      (__attribute__((address_space(3))) unsigned int*)l, 16, 0, 0);
}

__device__ __forceinline__ unsigned short f2bf(float x) {
  union { float f; unsigned int u; } v; v.f = x;
  unsigned int r = v.u + 0x7FFFu + ((v.u >> 16) & 1u);
  return (unsigned short)(r >> 16);
}

__device__ __forceinline__ float exp2_fast(float x) {
  return __builtin_amdgcn_exp2f(x);
}

// pack two fp32 -> bf16 pair in one dword: round-half-up + v_perm_b32
__device__ __forceinline__ unsigned int pack_bf2(float a, float b) {
  unsigned int ua = __builtin_bit_cast(unsigned int, a) + 0x8000u;
  unsigned int ub = __builtin_bit_cast(unsigned int, b) + 0x8000u;
  return __builtin_amdgcn_perm(ub, ua, 0x07060302u);
}

// ---------------- fused fp32->bf16 convert: x + in_proj_w + out_proj_w ----------------
__global__ void cvt3(const float* __restrict__ x, unsigned short* __restrict__ xd,
                     const float* __restrict__ w1, unsigned short* __restrict__ w1d,
                     const float* __restrict__ w2, unsigned short* __restrict__ w2d) {
  int i = blockIdx.x * 256 + threadIdx.x;
  const float* s; unsigned short* d; int off;
  if (i < 2097152)      { s = x;  d = xd;  off = i; }
  else if (i < 2883584) { s = w1; d = w1d; off = i - 2097152; }
  else                  { s = w2; d = w2d; off = i - 2883584; }
  float4 v = ((const float4*)s)[off];
  ushort4 o;
  o.x = f2bf(v.x); o.y = f2bf(v.y); o.z = f2bf(v.z); o.w = f2bf(v.w);
  ((ushort4*)d)[off] = o;
}

// ---------------- GEMM: C[m][n] = sum_k A[m][k]*B[n][k] + bias[n] ----------------
// 256x256 tile, BK=64, 512 threads (8 waves, 2M x 4N).
// REGISTER-PIPELINED 4-phase schedule: phase p issues ds_reads for phase p+1's
// fragments (double-buffered frag regs bX/bY, aP/aQ), then runs phase p's MFMAs
// on regs loaded LAST phase. Compiler emits counted lgkmcnt (only the new reads
// outstanding) before the cluster -> LDS pipe serves next phase's reads WHILE
// matrix pipe runs this phase's MFMAs (breaks the read->MFMA same-phase chain
// that serialized r2/r3 at ~32% MfmaUtil).
// Staging: 1 STAGE (2 gload_lds)/phase, calendar: ph0:B-kh1(t+1), ph1:A-kh0(t+2),
// ph2:B-kh0(t+2), ph3:A-kh1(t+2). Waits: vmcnt(8) at end of ph0 (lands kh1(t))
// and end of ph2 (lands kh0(t+1)) -- verified: cleared set == region read next
// phase. WAR: every restage is >=1 barrier after the region's last ds_read.
// ONE barrier per phase; no sched_barrier(0) (m141); XCD-swizzled blocks.
__global__ __launch_bounds__(512, 2)
void gemm_bt(const unsigned short* __restrict__ A0, const unsigned short* __restrict__ A1,
             const unsigned short* __restrict__ B0, const unsigned short* __restrict__ B1,
             const float* __restrict__ bias0, const float* __restrict__ bias1,
             void* __restrict__ out0, void* __restrict__ out1,
             int N, int K, int f32out, int qlim, float qs) {
  __shared__ unsigned short As[2][2][256 * 32];  // [buf][khalf][row*32+col] 64 KB
  __shared__ unsigned short Bs[2][2][256 * 32];  // 64 KB
  int br = blockIdx.z;
  const unsigned short* A = br ? A1 : A0;
  const unsigned short* B = br ? B1 : B0;
  const float* bias = br ? bias1 : bias0;
  void* outp = br ? out1 : out0;

  // XCD-aware swizzle of (x,y) within this z-slice
  int gx = gridDim.x, gy = gridDim.y;
  int nwg = gx * gy;
  int flat = blockIdx.y * gx + blockIdx.x;
  int cpx = nwg >> 3;  // nwg % 8 == 0 for all our grids (384, 128)
  int swb = (flat & 7) * cpx + (flat >> 3);
  int bxi = swb % gx, byi = swb / gx;

  int tid = threadIdx.x;
  int wave = tid >> 6, lane = tid & 63;
  int quad = lane >> 4, l16 = lane & 15;
  int wm = (wave >> 2) * 128;       // 2 M-groups of waves
  int wn = (wave & 3) * 64;         // 4 N-groups
  size_t bm = (size_t)byi * 256, bn = (size_t)bxi * 256;

  f32x4 acc[8][4];
  f32x4 zero = {0.f, 0.f, 0.f, 0.f};
#pragma unroll
  for (int i = 0; i < 8; i++)
#pragma unroll
    for (int j = 0; j < 4; j++) acc[i][j] = zero;

  // LDS read bases: frag (kh,mi): row = wm|wn + mi*16 + l16, swizzled chunk quad^((row>>1)&3)
  int swc = (quad ^ ((l16 >> 1) & 3)) * 16;
  const char* ArdB = (const char*)As + (wm + l16) * 64 + swc;
  const char* BrdB = (const char*)Bs + (wn + l16) * 64 + swc;

  // staging: thread t covers lds 16B-chunks t (rows 0..127) and 512+t (rows 128..255)
  // of each 16 KB (256x32) half-region; global source pre-swizzled to match reads.
  int row0 = tid >> 2, c0 = (tid & 3) ^ ((row0 >> 1) & 3);
  int row1 = row0 + 128, c1 = (tid & 3) ^ ((row1 >> 1) & 3);
  const char* Ag0 = (const char*)(A + (bm + row0) * (size_t)K) + c0 * 16;
  const char* Ag1 = (const char*)(A + (bm + row1) * (size_t)K) + c1 * 16;
  const char* Bg0 = (const char*)(B + (bn + row0) * (size_t)K) + c0 * 16;
  const char* Bg1 = (const char*)(B + (bn + row1) * (size_t)K) + c1 * 16;
  char* ldsA = (char*)As + tid * 16;
  char* ldsB = (char*)Bs + tid * 16;

#define STAGE_A(po_, kh_, koff_) do {                    \
    char* d_ = ldsA + (po_) + (kh_) * 16384;             \
    async_ld16(Ag0 + (koff_), d_);                       \
    async_ld16(Ag1 + (koff_), d_ + 8192); } while (0)
#define STAGE_B(po_, kh_, koff_) do {                    \
    char* d_ = ldsB + (po_) + (kh_) * 16384;             \
    async_ld16(Bg0 + (koff_), d_);                       \
    async_ld16(Bg1 + (koff_), d_ + 8192); } while (0)
#define LDA_F(po_, kh_, mi_) (*(const bf16x8*)(ArdB + (po_) + (kh_) * 16384 + (mi_) * 1024))
#define LDB_F(po_, kh_, ni_) (*(const bf16x8*)(BrdB + (po_) + (kh_) * 16384 + (ni_) * 1024))
// barrier + zero-cost compiler memory clobber: partitions memory-op ISSUE per
// phase (keeps vmcnt counting exact) without pinning the instruction scheduler.
#define BAR() do { __builtin_amdgcn_s_barrier(); asm volatile("" ::: "memory"); } while (0)
#define MFMAQ(mb_, B0_, B1_, B2_, B3_, A0_, A1_, A2_, A3_) do {                                        \
    acc[(mb_)+0][0] = __builtin_amdgcn_mfma_f32_16x16x32_bf16(B0_, A0_, acc[(mb_)+0][0], 0, 0, 0);     \
    acc[(mb_)+1][0] = __builtin_amdgcn_mfma_f32_16x16x32_bf16(B0_, A1_, acc[(mb_)+1][0], 0, 0, 0);     \
    acc[(mb_)+2][0] = __builtin_amdgcn_mfma_f32_16x16x32_bf16(B0_, A2_, acc[(mb_)+2][0], 0, 0, 0);     \
    acc[(mb_)+3][0] = __builtin_amdgcn_mfma_f32_16x16x32_bf16(B0_, A3_, acc[(mb_)+3][0], 0, 0, 0);     \
    acc[(mb_)+0][1] = __builtin_amdgcn_mfma_f32_16x16x32_bf16(B1_, A0_, acc[(mb_)+0][1], 0, 0, 0);     \
    acc[(mb_)+1][1] = __builtin_amdgcn_mfma_f32_16x16x32_bf16(B1_, A1_, acc[(mb_)+1][1], 0, 0, 0);     \
    acc[(mb_)+2][1] = __builtin_amdgcn_mfma_f32_16x16x32_bf16(B1_, A2_, acc[(mb_)+2][1], 0, 0, 0);     \
    acc[(mb_)+3][1] = __builtin_amdgcn_mfma_f32_16x16x32_bf16(B1_, A3_, acc[(mb_)+3][1], 0, 0, 0);     \
    acc[(mb_)+0][2] = __builtin_amdgcn_mfma_f32_16x16x32_bf16(B2_, A0_, acc[(mb_)+0][2], 0, 0, 0);     \
    acc[(mb_)+1][2] = __builtin_amdgcn_mfma_f32_16x16x32_bf16(B2_, A1_, acc[(mb_)+1][2], 0, 0, 0);     \
    acc[(mb_)+2][2] = __builtin_amdgcn_mfma_f32_16x16x32_bf16(B2_, A2_, acc[(mb_)+2][2], 0, 0, 0);     \
    acc[(mb_)+3][2] = __builtin_amdgcn_mfma_f32_16x16x32_bf16(B2_, A3_, acc[(mb_)+3][2], 0, 0, 0);     \
    acc[(mb_)+0][3] = __builtin_amdgcn_mfma_f32_16x16x32_bf16(B3_, A0_, acc[(mb_)+0][3], 0, 0, 0);     \
    acc[(mb_)+1][3] = __builtin_amdgcn_mfma_f32_16x16x32_bf16(B3_, A1_, acc[(mb_)+1][3], 0, 0, 0);     \
    acc[(mb_)+2][3] = __builtin_amdgcn_mfma_f32_16x16x32_bf16(B3_, A2_, acc[(mb_)+2][3], 0, 0, 0);     \
    acc[(mb_)+3][3] = __builtin_amdgcn_mfma_f32_16x16x32_bf16(B3_, A3_, acc[(mb_)+3][3], 0, 0, 0);     \
  } while (0)

  const int NT = K >> 6;  // 16 for K=1024

  // fragment register double-buffers (static names -> no scratch, rule 20)
  bf16x8 bX0, bX1, bX2, bX3;   // B kh0-of-current (or next tile at ph3)
  bf16x8 bY0, bY1, bY2, bY3;   // B kh1-of-current
  bf16x8 aP0, aP1, aP2, aP3;   // A set P
  bf16x8 aQ0, aQ1, aQ2, aQ3;   // A set Q

  // prologue: 7 STAGEs in steady-state issue order (14 loads)
  STAGE_A(0, 0, 0);       STAGE_B(0, 0, 0);        // kh0 t0
  STAGE_A(0, 1, 64);      STAGE_B(0, 1, 64);       // kh1 t0
  STAGE_A(32768, 0, 128); STAGE_B(32768, 0, 128);  // kh0 t1
  STAGE_A(32768, 1, 192);                          // kh1 t1 (A; B staged at [0,ph0])
  asm volatile("s_waitcnt vmcnt(10)" ::: "memory");  // oldest 4 = kh0 t0 landed
  BAR();
  // pre-loop frag reads: tile0 kh0 B + A mi0-3
  bX0 = LDB_F(0, 0, 0); bX1 = LDB_F(0, 0, 1); bX2 = LDB_F(0, 0, 2); bX3 = LDB_F(0, 0, 3);
  aP0 = LDA_F(0, 0, 0); aP1 = LDA_F(0, 0, 1); aP2 = LDA_F(0, 0, 2); aP3 = LDA_F(0, 0, 3);

  for (int j = 0; j < NT; ++j) {
    int po = (j & 1) * 32768;            // this tile's buffer
    int qo = po ^ 32768;                 // other buffer (tile j+1)
    int ko1 = ((j + 1 < NT) ? j + 1 : NT - 1) * 128;  // clamped (dest dead)
    int ko2 = ((j + 2 < NT) ? j + 2 : NT - 1) * 128;

    // ---- phase 0: read A kh0 mi4-7 (for ph1); MFMA kh0 mi0-3 (regs from prev ph3) ----
    aQ0 = LDA_F(po, 0, 4); aQ1 = LDA_F(po, 0, 5); aQ2 = LDA_F(po, 0, 6); aQ3 = LDA_F(po, 0, 7);
    STAGE_B(qo, 1, ko1 + 64);            // B kh1(t+1); dest dead since [j-1,ph2]
    __builtin_amdgcn_s_setprio(1);
    MFMAQ(0, bX0, bX1, bX2, bX3, aP0, aP1, aP2, aP3);
    __builtin_amdgcn_s_setprio(0);
    // lands kh1(t): 12 outstanding, oldest 4 = A/B kh1(t)
    asm volatile("s_waitcnt vmcnt(8)" ::: "memory");
    BAR();
    // ---- phase 1: read B kh1 + A kh1 mi0-3 (for ph2); MFMA kh0 mi4-7 ----
    bY0 = LDB_F(po, 1, 0); bY1 = LDB_F(po, 1, 1); bY2 = LDB_F(po, 1, 2); bY3 = LDB_F(po, 1, 3);
    aP0 = LDA_F(po, 1, 0); aP1 = LDA_F(po, 1, 1); aP2 = LDA_F(po, 1, 2); aP3 = LDA_F(po, 1, 3);
    STAGE_A(po, 0, ko2);                 // A kh0(t+2); dest dead since ph0
    __builtin_amdgcn_s_setprio(1);
    MFMAQ(4, bX0, bX1, bX2, bX3, aQ0, aQ1, aQ2, aQ3);
    __builtin_amdgcn_s_setprio(0);
    BAR();
    // ---- phase 2: read A kh1 mi4-7 (for ph3); MFMA kh1 mi0-3 ----
    aQ0 = LDA_F(po, 1, 4); aQ1 = LDA_F(po, 1, 5); aQ2 = LDA_F(po, 1, 6); aQ3 = LDA_F(po, 1, 7);
    STAGE_B(po, 0, ko2);                 // B kh0(t+2)
    __builtin_amdgcn_s_setprio(1);
    MFMAQ(0, bY0, bY1, bY2, bY3, aP0, aP1, aP2, aP3);
    __builtin_amdgcn_s_setprio(0);
    // lands kh0(t+1): 12 outstanding, oldest 4 = A/B kh0(t+1)
    asm volatile("s_waitcnt vmcnt(8)" ::: "memory");
    BAR();
    // ---- phase 3: read next tile kh0 B + A mi0-3 (for next ph0); MFMA kh1 mi4-7 ----
    bX0 = LDB_F(qo, 0, 0); bX1 = LDB_F(qo, 0, 1); bX2 = LDB_F(qo, 0, 2); bX3 = LDB_F(qo, 0, 3);
    aP0 = LDA_F(qo, 0, 0); aP1 = LDA_F(qo, 0, 1); aP2 = LDA_F(qo, 0, 2); aP3 = LDA_F(qo, 0, 3);
    STAGE_A(po, 1, ko2 + 64);            // A kh1(t+2); dest dead since ph2
    __builtin_amdgcn_s_setprio(1);
    MFMAQ(4, bY0, bY1, bY2, bY3, aQ0, aQ1, aQ2, aQ3);
    __builtin_amdgcn_s_setprio(0);
    BAR();
  }

#undef STAGE_A
#undef STAGE_B
#undef LDA_F
#undef LDB_F
#undef BAR
#undef MFMAQ

#pragma unroll
  for (int mi = 0; mi < 8; mi++) {
    size_t rowg = bm + wm + mi * 16 + l16;
#pragma unroll
    for (int ni = 0; ni < 4; ni++) {
      size_t col = bn + wn + ni * 16 + quad * 4;
      float s = ((int)col < qlim) ? qs : 1.0f;
      float4 bv = *(const float4*)&bias[col];
      f32x4 a = acc[mi][ni];
      if (f32out) {
        float4 o = {(a[0] + bv.x) * s, (a[1] + bv.y) * s,
                    (a[2] + bv.z) * s, (a[3] + bv.w) * s};
        *(float4*)&((float*)outp)[rowg * N + col] = o;
      } else {
        ushort4 o;
        o.x = f2bf((a[0] + bv.x) * s); o.y = f2bf((a[1] + bv.y) * s);
        o.z = f2bf((a[2] + bv.z) * s); o.w = f2bf((a[3] + bv.w) * s);
        *(ushort4*)&((unsigned short*)outp)[rowg * N + col] = o;
      }
    }
  }
}

// ---------------- transpose V slice of qkv -> VT (key-permuted, dual-branch) ----------------
__device__ __forceinline__ int kperm(int p) {
  return (p & 0xC3) | ((p & 0x0C) << 2) | ((p & 0x30) >> 2);
}
__global__ void transpose_v(const unsigned short* __restrict__ q0, unsigned short* __restrict__ v0, int W0,
                            const unsigned short* __restrict__ q1, unsigned short* __restrict__ v1, int W1,
                            int zsplit) {
  __shared__ unsigned short tile[64][33];
  int z = blockIdx.z;
  const unsigned short* qkv; unsigned short* vt; int W, wb, yy;
  if (z < zsplit) { qkv = q0; vt = v0; W = W0; wb = z; yy = blockIdx.y; }
  else { qkv = q1; vt = v1; W = W1; int t = z - zsplit; wb = t >> 2; yy = blockIdx.y + 4 * (t & 3); }
  int c0 = blockIdx.x * 32, w0 = yy * 64;
  const unsigned short* src = qkv + (size_t)wb * W * 3072 + 2048;
  for (int i = threadIdx.y; i < 64; i += 8)
    tile[i][threadIdx.x] = src[(size_t)(w0 + i) * 3072 + c0 + threadIdx.x];
  __syncthreads();
  unsigned short* dst = vt + (size_t)wb * 1024 * W;
  for (int i = threadIdx.y; i < 32; i += 8) {
    int p0 = threadIdx.x, p1 = threadIdx.x + 32;
    dst[(size_t)(c0 + i) * W + w0 + p0] = tile[kperm(p0)][i];
    dst[(size_t)(c0 + i) * W + w0 + p1] = tile[kperm(p1)][i];
  }
}

// ---------------- fused flash attention, S^T, max-free softmax, dual-branch ----------------
__global__ __launch_bounds__(256)
void attn_fused(const unsigned short* __restrict__ qkv0, const unsigned short* __restrict__ vt0,
                unsigned short* __restrict__ ao0, int W0, int nb0,
                const unsigned short* __restrict__ qkv1, const unsigned short* __restrict__ vt1,
                unsigned short* __restrict__ ao1, int W1) {
  __shared__ unsigned short Ks[64 * 64];
  __shared__ unsigned short Vs[64 * 64];
  __shared__ unsigned int   Ps[4][16 * 32];
  int bid = blockIdx.x;
  const unsigned short *qkv, *vtb0; unsigned short* ao; int W, rel;
  if (bid < nb0) { qkv = qkv0; vtb0 = vt0; ao = ao0; W = W0; rel = bid; }
  else           { qkv = qkv1; vtb0 = vt1; ao = ao1; W = W1; rel = bid - nb0; }
  int gx = W >> 7;                       // 2 or 8
  int shift = (gx == 2) ? 1 : 3;
  int bx = rel & (gx - 1);
  int wbh = rel >> shift;
  int wb = wbh >> 4, h = wbh & 15;

  int tid = threadIdx.x;
  int wave = tid >> 6, lane = tid & 63;
  int quad = lane >> 4, l16 = lane & 15;
  int swz = l16 & 7;
  int q0w = bx * 128 + wave * 32;

  const unsigned short* qb = qkv + (size_t)wb * W * 3072 + h * 64;
  const unsigned short* kb = qb + 1024;
  const unsigned short* vtb = vtb0 + (size_t)wbh * 64 * W;

  bf16x8 qf[2][2];
  for (int cb = 0; cb < 2; cb++)
    for (int ch = 0; ch < 2; ch++)
      qf[cb][ch] = *(const bf16x8*)(qb + (size_t)(q0w + cb * 16 + l16) * 3072 +
                                    ch * 32 + quad * 8);

  f32x4 zero = {0.f, 0.f, 0.f, 0.f};
  f32x4 O[2][4];
  for (int cb = 0; cb < 2; cb++)
    for (int g = 0; g < 4; g++) O[cb][g] = zero;
  float l_i[2] = {0.f, 0.f};

  for (int k0 = 0; k0 < W; k0 += 64) {
    __syncthreads();
    for (int j = 0; j < 2; j++) {
      int c = j * 256 + tid;
      int row = c >> 3, sl = c & 7, ss = sl ^ (row & 7);
      async_ld16(kb + (size_t)(k0 + row) * 3072 + ss * 8, (char*)Ks + c * 16);
      async_ld16(vtb + (size_t)row * W + k0 + ss * 8,     (char*)Vs + c * 16);
    }
    __syncthreads();

    bf16x8 ak[4][2], vf[4][2];
#pragma unroll
    for (int i = 0; i < 4; i++)
#pragma unroll
      for (int ch = 0; ch < 2; ch++) {
        int sl = (ch * 4 + quad) ^ swz;
        ak[i][ch] = *(const bf16x8*)&Ks[(i * 16 + l16) * 64 + sl * 8];
        vf[i][ch] = *(const bf16x8*)&Vs[(i * 16 + l16) * 64 + sl * 8];
      }

    for (int cb = 0; cb < 2; cb++) {
      unsigned int pk[8];
      float sm = 0.f;
#pragma unroll
      for (int sub = 0; sub < 4; sub++) {
        f32x4 z = zero;
        z = __builtin_amdgcn_mfma_f32_16x16x32_bf16(ak[sub][0], qf[cb][0], z, 0, 0, 0);
        z = __builtin_amdgcn_mfma_f32_16x16x32_bf16(ak[sub][1], qf[cb][1], z, 0, 0, 0);
        float p0 = exp2_fast(z[0]), p1 = exp2_fast(z[1]);
        float p2 = exp2_fast(z[2]), p3 = exp2_fast(z[3]);
        sm += (p0 + p1) + (p2 + p3);
        pk[((sub & 1) * 2) + (sub >> 1) * 4]     = pack_bf2(p0, p1);
        pk[((sub & 1) * 2) + (sub >> 1) * 4 + 1] = pack_bf2(p2, p3);
      }
      sm += __shfl_xor(sm, 16);
      sm += __shfl_xor(sm, 32);
      l_i[cb] += sm;

      unsigned int* pw = &Ps[wave][0];
      uint4 u0 = {pk[0], pk[1], pk[2], pk[3]};
      uint4 u1 = {pk[4], pk[5], pk[6], pk[7]};
      *(uint4*)&pw[l16 * 32 + ((2 * quad) ^ swz) * 4]     = u0;
      *(uint4*)&pw[l16 * 32 + ((2 * quad + 1) ^ swz) * 4] = u1;

      bf16x8 pf[2];
#pragma unroll
      for (int ch = 0; ch < 2; ch++) {
        uint4 u = *(const uint4*)&pw[l16 * 32 + ((ch * 4 + quad) ^ swz) * 4];
        pf[ch] = __builtin_bit_cast(bf16x8, u);
      }
#pragma unroll
      for (int g = 0; g < 4; g++) {
        O[cb][g] = __builtin_amdgcn_mfma_f32_16x16x32_bf16(pf[0], vf[g][0], O[cb][g], 0, 0, 0);
        O[cb][g] = __builtin_amdgcn_mfma_f32_16x16x32_bf16(pf[1], vf[g][1], O[cb][g], 0, 0, 0);
      }
    }
  }

  for (int cb = 0; cb < 2; cb++) {
    float inv = 1.0f / l_i[cb];
    float ivr[4];
    for (int r = 0; r < 4; r++) ivr[r] = __shfl(inv, quad * 4 + r);
    for (int r = 0; r < 4; r++) {
      size_t rowg = (size_t)wb * W + q0w + cb * 16 + quad * 4 + r;
      for (int g = 0; g < 4; g++)
        ao[rowg * 1024 + h * 64 + g * 16 + l16] = f2bf(O[cb][g][r] * ivr[r]);
    }
  }
}

// ---------------- host ----------------
extern "C" void kernel_launch(void* const* d_in, const int* in_sizes, int n_in,
                              void* d_out, int out_size, void* d_ws, size_t ws_size,
                              hipStream_t stream) {
  const int D = 1024, TD = 3072, M = 8192;
  const float QS = 0.125f * 1.44269504089f;  // softmax scale * log2(e)
  const size_t PER = 46137344;               // bf16 elems per branch
  bool comb = ws_size >= (size_t)2 * PER * 2;

  unsigned short* Xb[2]; unsigned short* Wb[2]; unsigned short* Ob[2];
  unsigned short* qkv[2]; unsigned short* vt[2];
  for (int b = 0; b < 2; b++) {
    unsigned short* base = (unsigned short*)d_ws + (comb ? b * PER : 0);
    Xb[b]  = base;
    Wb[b]  = Xb[b] + 8388608;
    Ob[b]  = Wb[b] + 3145728;
    qkv[b] = Ob[b] + 1048576;
    vt[b]  = qkv[b] + 25165824;
  }
  float* outp = (float*)d_out;
  const float* x[2]   = {(const float*)d_in[0], (const float*)d_in[1]};
  const float* ipw[2] = {(const float*)d_in[2], (const float*)d_in[6]};
  const float* ipb[2] = {(const float*)d_in[3], (const float*)d_in[7]};
  const float* opw[2] = {(const float*)d_in[4], (const float*)d_in[8]};
  const float* opb[2] = {(const float*)d_in[5], (const float*)d_in[9]};
  const int Wd[2] = {256, 1024};

  if (comb) {
    for (int b = 0; b < 2; b++)
      cvt3<<<12288, 256, 0, stream>>>(x[b], Xb[b], ipw[b], Wb[b], opw[b], Ob[b]);
    gemm_bt<<<dim3(TD / 256, M / 256, 2), 512, 0, stream>>>(
        Xb[0], Xb[1], Wb[0], Wb[1], ipb[0], ipb[1], qkv[0], qkv[1],
        TD, D, 0, D, QS);
    transpose_v<<<dim3(32, 4, 64), dim3(32, 8), 0, stream>>>(
        qkv[0], vt[0], 256, qkv[1], vt[1], 1024, 32);
    attn_fused<<<2048, 256, 0, stream>>>(
        qkv[0], vt[0], Xb[0], 256, 1024, qkv[1], vt[1], Xb[1], 1024);
    gemm_bt<<<dim3(D / 256, M / 256, 2), 512, 0, stream>>>(
        Xb[0], Xb[1], Ob[0], Ob[1], opb[0], opb[1], outp, outp + 8388608,
        D, D, 1, 0, 1.0f);
  } else {
    for (int b = 0; b < 2; b++) {
      int W = Wd[b], nwb = M / W;
      cvt3<<<12288, 256, 0, stream>>>(x[b], Xb[b], ipw[b], Wb[b], opw[b], Ob[b]);
      gemm_bt<<<dim3(TD / 256, M / 256, 1), 512, 0, stream>>>(
          Xb[b], Xb[b], Wb[b], Wb[b], ipb[b], ipb[b], qkv[b], qkv[b],
          TD, D, 0, D, QS);
      if (b == 0)
        transpose_v<<<dim3(32, 4, 32), dim3(32, 8), 0, stream>>>(
            qkv[b], vt[b], W, qkv[b], vt[b], W, 32);
      else
        transpose_v<<<dim3(32, 4, 32), dim3(32, 8), 0, stream>>>(
            qkv[b], vt[b], W, qkv[b], vt[b], W, 0);
      int nb = (W >> 7) * nwb * 16;
      attn_fused<<<nb, 256, 0, stream>>>(
          qkv[b], vt[b], Xb[b], W, nb, qkv[b], vt[b], Xb[b], W);
      gemm_bt<<<dim3(D / 256, M / 256, 1), 512, 0, stream>>>(
          Xb[b], Xb[b], Ob[b], Ob[b], opb[b], opb[b],
          outp + (size_t)b * 8388608, outp + (size_t)b * 8388608,
          D, D, 1, 0, 1.0f);
    }
  }
}